// Round 9
// baseline (61.548 us; speedup 1.0000x reference)
//
#include <hip/hip_runtime.h>
#include <math.h>

#define HH 2048
#define WW 2048

// Gaussian sigma=2, 5 taps, normalized
#define GW0 0.15246914402033867f
#define GW1 0.22184129554377693f
#define GW2 0.25137912086578894f

typedef float f4 __attribute__((ext_vector_type(4)));

#define NWI 2040    // interior waves: 8 strips x 255 row-groups (rows 4..2043)
#define NWB 16      // border waves: 8 strips x {y0=0, y0=2044}, T=4
#define NACC (NWI + NWB)

struct R8 { float v[8]; };
struct R6 { float v[6]; };
struct Raw { f4 a, b, c; };

// ---------------- shared helpers ----------------
__device__ __forceinline__ R8 make_h(const Raw& R, bool edgew, bool le, bool re) {
    float w[12] = {R.a.x, R.a.y, R.a.z, R.a.w, R.b.x, R.b.y, R.b.z, R.b.w,
                   R.c.x, R.c.y, R.c.z, R.c.w};
    if (edgew) {
        if (le) { w[0] = R.c.x; w[1] = R.b.w; w[2] = R.b.z; w[3] = R.b.y; }   // reflect left
        if (re) { w[8] = R.b.z; w[9] = R.b.y; w[10] = R.b.x; w[11] = R.a.w; } // reflect right
    }
    R8 h;
    #pragma unroll
    for (int j = 0; j < 8; ++j)
        h.v[j] = GW0 * (w[j] + w[j + 4]) + GW1 * (w[j + 1] + w[j + 3]) + GW2 * w[j + 2];
    return h;
}

__device__ __forceinline__ R8 vg5(const R8& a, const R8& b, const R8& c, const R8& d, const R8& e_,
                                  bool edgew, bool le, bool re) {
    R8 o;
    #pragma unroll
    for (int j = 0; j < 8; ++j)
        o.v[j] = GW0 * (a.v[j] + e_.v[j]) + GW1 * (b.v[j] + d.v[j]) + GW2 * c.v[j];
    if (edgew) {
        if (le) { o.v[0] = o.v[2]; o.v[1] = o.v[2]; }
        if (re) { o.v[6] = o.v[5]; o.v[7] = o.v[5]; }
    }
    return o;
}

// refactored first sobel via column sums: 8-wide in -> 6-wide out
__device__ __forceinline__ void sobel1(const R8& u, const R8& m, const R8& d, R6& ox, R6& oy,
                                       bool edgew, bool le, bool re) {
    float E[8], F[8];
    #pragma unroll
    for (int j = 0; j < 8; ++j) {
        E[j] = u.v[j] + 2.f * m.v[j] + d.v[j];
        F[j] = d.v[j] - u.v[j];
    }
    #pragma unroll
    for (int j = 0; j < 6; ++j) {
        ox.v[j] = (E[j + 2] - E[j]) * 0.125f;
        oy.v[j] = (F[j] + 2.f * F[j + 1] + F[j + 2]) * 0.125f;
    }
    if (edgew) {
        if (le) { ox.v[0] = ox.v[1]; oy.v[0] = oy.v[1]; }
        if (re) { ox.v[5] = ox.v[4]; oy.v[5] = oy.v[4]; }
    }
}

// ============================ interior kernel ============================
__global__ __launch_bounds__(256) void steal_interior(const float* __restrict__ pred,
                                                      const float* __restrict__ lab,
                                                      float* __restrict__ acc) {
    const int lane = threadIdx.x & 63;
    const int wid  = (blockIdx.x << 2) + (threadIdx.x >> 6);   // 0..2039
    const int w  = wid & 7;
    const int rg = wid >> 3;
    const int y0 = 4 + rg * 8;                // rows y0..y0+7 in [4, 2043]
    const int xb = w * 256 + lane * 4;
    const int xl = max(xb - 4, 0);
    const int xr = min(xb + 4, WW - 4);
    const bool edgew = (w == 0) || (w == 7);
    const bool le = (w == 0) && (lane == 0);
    const bool re = (w == 7) && (lane == 63);

    const float T1f = 0.41421356237309503f;   // tan(pi/8)
    const float T3f = 2.41421356237309510f;   // tan(3pi/8)

    R8 h[5], bl[3], er[5];
    R6 gzx[3], gzy[3];
    float lsum = 0.f;

    #pragma unroll
    for (int s = 0; s < 16; ++s) {
        // ---- new h row: lab row y0-4+s (always in [0,2047], no reflect) ----
        {
            const float* row = lab + (size_t)(y0 - 4 + s) * WW;
            Raw rw;
            rw.a = *(const f4*)(row + xl);
            rw.b = *(const f4*)(row + xb);
            rw.c = *(const f4*)(row + xr);
            h[s % 5] = make_h(rw, edgew, le, re);
        }

        if (s >= 4) {
            const int j = s - 4;              // blur row y0-2+j ; e row y0-2+j
            bl[j % 3] = vg5(h[j % 5], h[(j + 1) % 5], h[(j + 2) % 5],
                            h[(j + 3) % 5], h[(j + 4) % 5], edgew, le, re);
            // e row (rows y0-2..y0+9 all real in interior)
            const float* row = pred + (size_t)(y0 - 2 + j) * WW;
            f4 A = *(const f4*)(row + xl);
            f4 B = *(const f4*)(row + xb);
            f4 C = *(const f4*)(row + xr);
            float ww[8] = {A.z, A.w, B.x, B.y, B.z, B.w, C.x, C.y};
            R8 e_;
            #pragma unroll
            for (int q = 0; q < 8; ++q) e_.v[q] = __expf(ww[q] * 10.f);
            if (edgew) {
                if (le) { e_.v[0] = 0.f; e_.v[1] = 0.f; }
                if (re) { e_.v[6] = 0.f; e_.v[7] = 0.f; }
            }
            er[j % 5] = e_;
        }

        if (s >= 6) {
            const int g = s - 6;              // gx/gy row y0-1+g
            sobel1(bl[g % 3], bl[(g + 1) % 3], bl[(g + 2) % 3],
                   gzx[g % 3], gzy[g % 3], edgew, le, re);
        }

        if (s >= 8) {
            const int i = s - 8;              // output row y0+i
            const R6& X0 = gzx[i % 3];
            const R6& X1 = gzx[(i + 1) % 3];
            const R6& X2 = gzx[(i + 2) % 3];
            const R6& Y0 = gzy[i % 3];
            const R6& Y1 = gzy[(i + 1) % 3];
            const R6& Y2 = gzy[(i + 2) % 3];
            float Cx[6], Cy[6], Dy[6];
            #pragma unroll
            for (int j = 0; j < 6; ++j) {
                Cx[j] = X0.v[j] + 2.f * X1.v[j] + X2.v[j];
                Cy[j] = Y0.v[j] + 2.f * Y1.v[j] + Y2.v[j];
                Dy[j] = Y2.v[j] - Y0.v[j];
            }
            const R8& eA = er[i % 5];
            const R8& eB = er[(i + 1) % 5];
            const R8& eC = er[(i + 2) % 5];
            const R8& eD = er[(i + 3) % 5];
            const R8& eE = er[(i + 4) % 5];
            float P[8];
            P[0] = eC.v[0];
            #pragma unroll
            for (int j = 1; j < 8; ++j) P[j] = P[j - 1] + eC.v[j];

            f4 pc4 = *(const f4*)(pred + (size_t)(y0 + i) * WW + xb);
            float pcv[4] = {pc4.x, pc4.y, pc4.z, pc4.w};

            #pragma unroll
            for (int k = 0; k < 4; ++k) {
                float gxx = (Cx[k + 2] - Cx[k]) * 0.125f;
                float gxy = (Cy[k + 2] - Cy[k]) * 0.125f;
                float gyy = (Dy[k] + 2.f * Dy[k + 1] + Dy[k + 2]) * 0.125f;

                float sg = -(gxy + 1e-6f);
                float sgn = (sg > 0.f) ? 1.f : ((sg < 0.f) ? -1.f : 0.f);
                float rt = gyy * sgn * __builtin_amdgcn_rcpf(gxx + 1e-6f);

                float hs  = (k == 0) ? P[4] : (P[k + 4] - P[k - 1]);
                float vs  = eA.v[k+2] + eB.v[k+2] + eC.v[k+2] + eD.v[k+2] + eE.v[k+2];
                float dls = eA.v[k]   + eB.v[k+1] + eC.v[k+2] + eD.v[k+3] + eE.v[k+4];
                float dcs = eA.v[k+4] + eB.v[k+3] + eC.v[k+2] + eD.v[k+1] + eE.v[k];

                bool isH = (rt >= -T1f) && (rt < T1f);
                bool isL = (rt >=  T1f) && (rt < T3f);
                bool isC = (rt >= -T3f) && (rt < -T1f);
                bool has = isH || isL || isC || (rt >= T3f) || (rt < -T3f);  // false only NaN
                float resp = isH ? hs : (isL ? dls : (isC ? dcs : vs));
                float lv = pcv[k] * 10.f - __logf(resp + 1e-6f);
                lsum += has ? lv : 0.f;
            }
        }
    }

    #pragma unroll
    for (int off = 32; off; off >>= 1) lsum += __shfl_down(lsum, off, 64);
    if (lane == 0) acc[wid] = lsum;
}

// ============================ border kernel (R4 staged, proven) ============================
__device__ __forceinline__ int reflect_row(int vr) {
    return vr < 0 ? -vr : (vr >= HH ? 2 * HH - 2 - vr : vr);
}

__device__ __forceinline__ Raw load_row3(const float* __restrict__ p, int r, int xb) {
    const float* row = p + (size_t)r * WW;
    Raw o;
    o.a = *(const f4*)(row + max(xb - 4, 0));
    o.b = *(const f4*)(row + xb);
    o.c = *(const f4*)(row + min(xb + 4, WW - 4));
    return o;
}

__device__ __forceinline__ void sobelB(const R8& u, const R8& m, const R8& d, R6& ox, R6& oy,
                                       bool edgew, bool le, bool re) {
    #pragma unroll
    for (int j = 0; j < 6; ++j) {
        ox.v[j] = ((u.v[j+2] - u.v[j]) + 2.f*(m.v[j+2] - m.v[j]) + (d.v[j+2] - d.v[j])) * 0.125f;
        oy.v[j] = ((d.v[j] - u.v[j]) + 2.f*(d.v[j+1] - u.v[j+1]) + (d.v[j+2] - u.v[j+2])) * 0.125f;
    }
    if (edgew) {
        if (le) { ox.v[0] = ox.v[1]; oy.v[0] = oy.v[1]; }
        if (re) { ox.v[5] = ox.v[4]; oy.v[5] = oy.v[4]; }
    }
}

__device__ __forceinline__ R8 erowB(const float* __restrict__ pred, int ry, int xb,
                                    bool edgew, bool le, bool re) {
    R8 o;
    if (ry < 0 || ry >= HH) {
        #pragma unroll
        for (int j = 0; j < 8; ++j) o.v[j] = 0.f;
        return o;
    }
    const float* row = pred + (size_t)ry * WW;
    f4 A = *(const f4*)(row + max(xb - 4, 0));
    f4 B = *(const f4*)(row + xb);
    f4 C = *(const f4*)(row + min(xb + 4, WW - 4));
    float w[8] = {A.z, A.w, B.x, B.y, B.z, B.w, C.x, C.y};
    #pragma unroll
    for (int j = 0; j < 8; ++j) o.v[j] = __expf(w[j] * 10.f);
    if (edgew) {
        if (le) { o.v[0] = 0.f; o.v[1] = 0.f; }
        if (re) { o.v[6] = 0.f; o.v[7] = 0.f; }
    }
    return o;
}

__global__ __launch_bounds__(256) void steal_border(const float* __restrict__ pred,
                                                    const float* __restrict__ lab,
                                                    float* __restrict__ acc) {
    const int lane = threadIdx.x & 63;
    const int b = (blockIdx.x << 2) + (threadIdx.x >> 6);   // 0..15
    const int sx = b & 7;
    const int y0 = (b >> 3) ? 2044 : 0;
    const int xb = sx * 256 + lane * 4;
    const bool edgew = (sx == 0) || (sx == 7);
    const bool le = (sx == 0) && (lane == 0);
    const bool re = (sx == 7) && (lane == 63);

    const float T1f = 0.41421356237309503f;
    const float T3f = 2.41421356237309510f;

    R8 H0, H1, H2, H3, b0, b1;
    R6 gx0, gy0, gx1, gy1;
    {
        R8 A0 = make_h(load_row3(lab, reflect_row(y0 - 4), xb), edgew, le, re);
        R8 A1 = make_h(load_row3(lab, reflect_row(y0 - 3), xb), edgew, le, re);
        R8 A2 = make_h(load_row3(lab, reflect_row(y0 - 2), xb), edgew, le, re);
        R8 A3 = make_h(load_row3(lab, reflect_row(y0 - 1), xb), edgew, le, re);
        H0 = make_h(load_row3(lab, y0 + 0, xb), edgew, le, re);
        H1 = make_h(load_row3(lab, y0 + 1, xb), edgew, le, re);
        H2 = make_h(load_row3(lab, y0 + 2, xb), edgew, le, re);
        H3 = make_h(load_row3(lab, y0 + 3, xb), edgew, le, re);
        R8 bm2 = vg5(A0, A1, A2, A3, H0, edgew, le, re);
        R8 bm1 = vg5(A1, A2, A3, H0, H1, edgew, le, re);
        b0 = vg5(A2, A3, H0, H1, H2, edgew, le, re);
        b1 = vg5(A3, H0, H1, H2, H3, edgew, le, re);
        if (y0 > 0) {
            sobelB(bm2, bm1, b0, gx0, gy0, edgew, le, re);
            sobelB(bm1, b0,  b1, gx1, gy1, edgew, le, re);
        } else {
            sobelB(b0, b0, b1, gx1, gy1, edgew, le, re);
            gx0 = gx1; gy0 = gy1;
        }
    }

    R8 e0 = erowB(pred, y0 - 2, xb, edgew, le, re);
    R8 e1 = erowB(pred, y0 - 1, xb, edgew, le, re);
    R8 e2 = erowB(pred, y0 + 0, xb, edgew, le, re);
    R8 e3 = erowB(pred, y0 + 1, xb, edgew, le, re);

    float lsum = 0.f;

    #pragma unroll
    for (int i = 0; i < 4; ++i) {
        const int y = y0 + i;

        R8 bn;
        if (y + 2 < HH) {
            R8 hn = make_h(load_row3(lab, reflect_row(y + 4), xb), edgew, le, re);
            bn = vg5(H0, H1, H2, H3, hn, edgew, le, re);
            H0 = H1; H1 = H2; H2 = H3; H3 = hn;
        } else bn = b1;

        R6 gxn, gyn;
        if (y + 1 < HH) sobelB(b0, b1, bn, gxn, gyn, edgew, le, re);
        else { gxn = gx1; gyn = gy1; }

        R8 en = erowB(pred, y + 2, xb, edgew, le, re);

        f4 pc4 = *(const f4*)(pred + (size_t)y * WW + xb);
        float pcv[4] = {pc4.x, pc4.y, pc4.z, pc4.w};

        #pragma unroll
        for (int k = 0; k < 4; ++k) {
            float gxx = ((gx0.v[k+2]-gx0.v[k]) + 2.f*(gx1.v[k+2]-gx1.v[k]) +
                         (gxn.v[k+2]-gxn.v[k])) * 0.125f;
            float gxy = ((gy0.v[k+2]-gy0.v[k]) + 2.f*(gy1.v[k+2]-gy1.v[k]) +
                         (gyn.v[k+2]-gyn.v[k])) * 0.125f;
            float gyy = ((gyn.v[k]-gy0.v[k]) + 2.f*(gyn.v[k+1]-gy0.v[k+1]) +
                         (gyn.v[k+2]-gy0.v[k+2])) * 0.125f;
            float sg = -(gxy + 1e-6f);
            float sgn = (sg > 0.f) ? 1.f : ((sg < 0.f) ? -1.f : 0.f);
            float rt = gyy * sgn * __builtin_amdgcn_rcpf(gxx + 1e-6f);

            float hs  = e2.v[k] + e2.v[k+1] + e2.v[k+2] + e2.v[k+3] + e2.v[k+4];
            float vs  = e0.v[k+2] + e1.v[k+2] + e2.v[k+2] + e3.v[k+2] + en.v[k+2];
            float dls = e0.v[k]   + e1.v[k+1] + e2.v[k+2] + e3.v[k+3] + en.v[k+4];
            float dcs = e0.v[k+4] + e1.v[k+3] + e2.v[k+2] + e3.v[k+1] + en.v[k];

            bool isH = (rt >= -T1f) && (rt < T1f);
            bool isL = (rt >=  T1f) && (rt < T3f);
            bool isC = (rt >= -T3f) && (rt < -T1f);
            bool has = isH || isL || isC || (rt >= T3f) || (rt < -T3f);
            float resp = isH ? hs : (isL ? dls : (isC ? dcs : vs));
            float lv = pcv[k] * 10.f - __logf(resp + 1e-6f);
            lsum += has ? lv : 0.f;
        }

        b0 = b1; b1 = bn;
        gx0 = gx1; gx1 = gxn; gy0 = gy1; gy1 = gyn;
        e0 = e1; e1 = e2; e2 = e3; e3 = en;
    }

    #pragma unroll
    for (int off = 32; off; off >>= 1) lsum += __shfl_down(lsum, off, 64);
    if (lane == 0) acc[NWI + b] = lsum;
}

__global__ __launch_bounds__(256) void steal_finalize(const float* __restrict__ acc,
                                                      float* __restrict__ out, int n) {
    __shared__ double sd[256];
    double a = 0.0;
    int n4 = n >> 2;
    for (int i = threadIdx.x; i < n4; i += 256) {
        f4 v = *(const f4*)(acc + i * 4);
        a += (double)v.x + (double)v.y + (double)v.z + (double)v.w;
    }
    for (int i = (n4 << 2) + threadIdx.x; i < n; i += 256) a += (double)acc[i];
    sd[threadIdx.x] = a;
    __syncthreads();
    for (int s = 128; s > 0; s >>= 1) {
        if (threadIdx.x < s) sd[threadIdx.x] += sd[threadIdx.x + s];
        __syncthreads();
    }
    if (threadIdx.x == 0) out[0] = (float)(-sd[0] / 4194304.0);
}

extern "C" void kernel_launch(void* const* d_in, const int* in_sizes, int n_in,
                              void* d_out, int out_size, void* d_ws, size_t ws_size,
                              hipStream_t stream) {
    const float* pred = (const float*)d_in[0];   // (1,1,2048,2048) f32
    const float* lab  = (const float*)d_in[1];   // (1,2048,2048) f32
    float* out = (float*)d_out;                  // scalar f32
    float* ws  = (float*)d_ws;

    steal_border<<<NWB / 4, 256, 0, stream>>>(pred, lab, ws);       // 4 blocks
    steal_interior<<<NWI / 4, 256, 0, stream>>>(pred, lab, ws);     // 510 blocks
    steal_finalize<<<1, 256, 0, stream>>>(ws, out, NACC);
}